// Round 6
// baseline (165.663 us; speedup 1.0000x reference)
//
#include <hip/hip_runtime.h>

#define GAT_H 12
#define GAT_N 4096
#define GAT_F 64
#define JB    512                  // j-slice per block
#define NJB   (GAT_N / JB)         // 8
#define RPB   8                    // rows per block
#define HPW   3                    // heads per wave
#define LOG2E 1.4426950408889634f
#define TAB_OFF  1024                              // floats into d_ws
#define PART_OFF (TAB_OFF + GAT_N * GAT_H * 2)     // floats into d_ws

__device__ __forceinline__ float rdlane(float v, int l) {
    return __uint_as_float(__builtin_amdgcn_readlane(__float_as_uint(v), l));
}

// Prep: blocks 0..11 compute s_h = <W_h, a_src_h>, d_h = <W_h, a_dst_h>.
// Block 12 computes mean(x) (fallback for neighborless rows -> uniform attn).
__global__ __launch_bounds__(64) void gat_prep(const float* __restrict__ W,
                                               const float* __restrict__ a,
                                               const float* __restrict__ x,
                                               float* __restrict__ sd) {
    const int b = blockIdx.x;
    const int f = threadIdx.x;
    if (b < GAT_H) {
        const float wf = W[b * GAT_F + f];
        float ps = wf * a[b * 2 * GAT_F + f];
        float pd = wf * a[b * 2 * GAT_F + GAT_F + f];
        #pragma unroll
        for (int off = 32; off > 0; off >>= 1) {
            ps += __shfl_xor(ps, off, 64);
            pd += __shfl_xor(pd, off, 64);
        }
        if (f == 0) { sd[b] = ps; sd[GAT_H + b] = pd; }
    } else {
        float s = 0.0f;
        #pragma unroll
        for (int j = 0; j < GAT_N / 64; ++j) s += x[j * 64 + f];
        #pragma unroll
        for (int off = 32; off > 0; off >>= 1) s += __shfl_xor(s, off, 64);
        if (f == 0) sd[2 * GAT_H] = s * (1.0f / GAT_N);
    }
}

// Table, layout [jb][h][jl] (jl = j % 512): {B,D} = {exp2(L*d_h*x_j),
// exp2(0.2L*d_h*x_j)}, swapped when d_h<0 so consumer compare is fixed.
__global__ __launch_bounds__(256) void gat_tab(const float* __restrict__ x,
                                               const float* __restrict__ sd,
                                               float2* __restrict__ tab) {
    const int t  = blockIdx.x * 256 + threadIdx.x;      // 0..49151
    const int jb = t / (GAT_H * JB);
    const int h  = (t / JB) % GAT_H;
    const int jl = t % JB;
    const float d = sd[GAT_H + h];
    const float q = LOG2E * d * x[jb * JB + jl];
    const float B = __builtin_amdgcn_exp2f(q);
    const float D = __builtin_amdgcn_exp2f(0.2f * q);
    tab[t] = (d > 0.0f) ? make_float2(B, D) : make_float2(D, B);
}

// Main: 4096 blocks = 512 row-blocks x 8 j-slices. Block = 8 rows x 512 j.
// Table slice (48 KB) staged to LDS ONCE; hot loop has ZERO barriers.
// Waves split the 12 heads (3 each); acc = 8r x 3h x {den,num} = 48 VGPRs.
// Per-(r,h) consts U,RA in SGPRs (lane-parallel compute + readlane); the
// per-row branch factor cancels in num/den. Partials to global ws.
// Body per (j,r,h): v_cmp(sgpr) + v_mul + v_cndmask + 2 v_fma. No trans.
__global__ __launch_bounds__(256, 3) void gat_main(const float* __restrict__ x,
                                                   const int* __restrict__ adj,
                                                   const float* __restrict__ sd,
                                                   const float2* __restrict__ tab,
                                                   float2* __restrict__ part) {
    __shared__ float2 tb[GAT_H * JB];   // 48 KB
    const int tid  = threadIdx.x;
    const int lane = tid & 63;
    const int wq   = tid >> 6;
    const int rb   = blockIdx.x >> 3;
    const int jb   = blockIdx.x & 7;
    const int row0 = rb * RPB;
    const int j0   = jb * JB;

    // Stage table slice: 3072 float4, coalesced, conflict-free.
    {
        const float4* g = (const float4*)(tab + (size_t)jb * (GAT_H * JB));
        float4* l = (float4*)tb;
        #pragma unroll
        for (int k = 0; k < 12; ++k) l[k * 256 + tid] = g[k * 256 + tid];
    }

    // Lane-parallel per-(r,k) constants -> SGPRs. 48 items: (r, k, {U,RA}).
    float sU[RPB][HPW], sRA[RPB][HPW];
    {
        const int it  = (lane < 48) ? lane : 0;
        const int r   = it / 6;
        const int rem = it % 6;
        const int k   = rem >> 1;
        const int w   = rem & 1;
        const int h   = wq * HPW + k;
        const float xi = x[row0 + r];
        const float dh = sd[GAT_H + h];
        const float zi = xi * sd[h];
        const float U  = -zi * __builtin_amdgcn_rcpf(dh);
        const float RA = __builtin_amdgcn_exp2f(((dh > 0.f) ? -0.8f : 0.8f) * LOG2E * zi);
        const float val = w ? RA : U;
        #pragma unroll
        for (int r2 = 0; r2 < RPB; ++r2)
            #pragma unroll
            for (int k2 = 0; k2 < HPW; ++k2) {
                sU[r2][k2]  = rdlane(val, r2 * 6 + k2 * 2);
                sRA[r2][k2] = rdlane(val, r2 * 6 + k2 * 2 + 1);
            }
    }

    // x values for this wave's j columns (lane owns 4 consecutive j per chunk).
    float4 xj4[2];
    xj4[0] = ((const float4*)(x + j0))[lane];
    xj4[1] = ((const float4*)(x + j0))[64 + lane];

    // adj chunk 0 (8 rows x int4/lane), coalesced; chunk 1 issued later.
    int4 A0[RPB], A1[RPB];
    #pragma unroll
    for (int r = 0; r < RPB; ++r)
        A0[r] = ((const int4*)(adj + (size_t)(row0 + r) * GAT_N + j0))[lane];

    float2 acc[RPB][HPW];
    #pragma unroll
    for (int r = 0; r < RPB; ++r)
        #pragma unroll
        for (int k = 0; k < HPW; ++k) acc[r][k] = make_float2(0.0f, 0.0f);

    __syncthreads();   // table staged — the ONLY pre-epilogue barrier

    // Issue chunk-1 adj loads so they fly under chunk-0 compute.
    #pragma unroll
    for (int r = 0; r < RPB; ++r)
        A1[r] = ((const int4*)(adj + (size_t)(row0 + r) * GAT_N + j0))[64 + lane];

    #pragma unroll
    for (int c = 0; c < 2; ++c) {
        // Table pairs for this chunk: per head, 2x b128 (lane's 4 j).
        float2 P[HPW][4];
        #pragma unroll
        for (int k = 0; k < HPW; ++k) {
            const float4* lp = (const float4*)(tb + (wq * HPW + k) * JB + c * 256 + lane * 4);
            const float4 p01 = lp[0], p23 = lp[1];
            P[k][0] = make_float2(p01.x, p01.y);
            P[k][1] = make_float2(p01.z, p01.w);
            P[k][2] = make_float2(p23.x, p23.y);
            P[k][3] = make_float2(p23.z, p23.w);
        }
        #pragma unroll
        for (int e = 0; e < 4; ++e) {
            const float xj = (e == 0) ? xj4[c].x : (e == 1) ? xj4[c].y
                           : (e == 2) ? xj4[c].z : xj4[c].w;
            #pragma unroll
            for (int r = 0; r < RPB; ++r) {
                const int4 av = c ? A1[r] : A0[r];
                const int  ai = (e == 0) ? av.x : (e == 1) ? av.y
                              : (e == 2) ? av.z : av.w;
                const float m01 = (float)ai;       // adj in {0,1}
                const float xm  = xj * m01;
                #pragma unroll
                for (int k = 0; k < HPW; ++k) {
                    const bool  sel = xj > sU[r][k];
                    const float E   = sel ? P[k][e].x : P[k][e].y * sRA[r][k];
                    acc[r][k].x = fmaf(E, m01, acc[r][k].x);
                    acc[r][k].y = fmaf(E, xm,  acc[r][k].y);
                }
            }
        }
    }

    // Reduce each cell across the wave; lane 0 stores partials.
    #pragma unroll
    for (int r = 0; r < RPB; ++r)
        #pragma unroll
        for (int k = 0; k < HPW; ++k) {
            float dn = acc[r][k].x, nm = acc[r][k].y;
            #pragma unroll
            for (int off = 32; off > 0; off >>= 1) {
                dn += __shfl_xor(dn, off, 64);
                nm += __shfl_xor(nm, off, 64);
            }
            acc[r][k] = make_float2(dn, nm);
        }
    if (lane == 0) {
        #pragma unroll
        for (int r = 0; r < RPB; ++r)
            #pragma unroll
            for (int k = 0; k < HPW; ++k)
                part[((size_t)(row0 + r) * GAT_H + wq * HPW + k) * NJB + jb] = acc[r][k];
    }
}

// Combine: block = 4 rows. Sum 8 j-slice partials, fallback, out = c * W.
__global__ __launch_bounds__(256) void gat_comb(const float2* __restrict__ part,
                                                const float* __restrict__ sd,
                                                const float* __restrict__ W,
                                                float* __restrict__ out) {
    __shared__ float2 pp[4 * GAT_H * NJB];   // 384 float2
    __shared__ float  cs[4 * GAT_H];
    const int tid = threadIdx.x;
    if (tid < 192)
        ((float4*)pp)[tid] =
            ((const float4*)(part + (size_t)blockIdx.x * 4 * GAT_H * NJB))[tid];
    __syncthreads();
    if (tid < 4 * GAT_H) {
        const int r = tid / GAT_H, h = tid % GAT_H;
        float dn = 0.0f, nm = 0.0f;
        #pragma unroll
        for (int u = 0; u < NJB; ++u) {
            const float2 p = pp[(r * GAT_H + h) * NJB + u];
            dn += p.x; nm += p.y;
        }
        cs[tid] = dn > 0.0f ? nm / dn : sd[2 * GAT_H];
    }
    __syncthreads();
    const size_t base = (size_t)blockIdx.x * 4 * GAT_H * GAT_F;
    #pragma unroll
    for (int it = 0; it < 3; ++it) {
        const int pos = it * 256 + tid;        // 0..767 within... 3072 total
        #pragma unroll
        for (int rr = 0; rr < 4; ++rr) {
            const int flat = rr * 768 + pos;
            const int rem  = flat % 768;
            out[base + flat] = cs[(flat / 768) * GAT_H + rem / GAT_F] * W[rem];
        }
    }
}

extern "C" void kernel_launch(void* const* d_in, const int* in_sizes, int n_in,
                              void* d_out, int out_size, void* d_ws, size_t ws_size,
                              hipStream_t stream) {
    const float* x   = (const float*)d_in[0];
    const int*   adj = (const int*)d_in[1];
    const float* W   = (const float*)d_in[2];
    const float* a   = (const float*)d_in[3];
    float*  out  = (float*)d_out;
    float*  sd   = (float*)d_ws;                          // 25 floats
    float2* tab  = (float2*)((float*)d_ws + TAB_OFF);     // 384 KB
    float2* part = (float2*)((float*)d_ws + PART_OFF);    // 3 MB

    gat_prep<<<13, 64, 0, stream>>>(W, a, x, sd);
    gat_tab<<<(GAT_N * GAT_H) / 256, 256, 0, stream>>>(x, sd, tab);
    gat_main<<<(GAT_N / RPB) * NJB, 256, 0, stream>>>(x, adj, sd, tab, part);
    gat_comb<<<GAT_N / 4, 256, 0, stream>>>(part, sd, W, out);
}

// Round 7
// 142.182 us; speedup vs baseline: 1.1651x; 1.1651x over previous
//
#include <hip/hip_runtime.h>

#define GAT_H 12
#define GAT_N 4096
#define GAT_F 64
#define JB    1024                 // j-slice per block
#define NJB   (GAT_N / JB)         // 4
#define RPB   4                    // rows per block
#define HPW   3                    // heads per wave
#define CH    128                  // j per chunk (lane owns 2)
#define NCH   (JB / CH)            // 8
#define LOG2E 1.4426950408889634f
#define TAB_OFF  1024                              // floats into d_ws
#define PART_OFF (TAB_OFF + GAT_N * GAT_H * 2)     // floats into d_ws

__device__ __forceinline__ float rdlane(float v, int l) {
    return __uint_as_float(__builtin_amdgcn_readlane(__float_as_uint(v), l));
}

// Prep: blocks 0..11 compute s_h = <W_h, a_src_h>, d_h = <W_h, a_dst_h>.
// Block 12 computes mean(x) (fallback for neighborless rows -> uniform attn).
__global__ __launch_bounds__(64) void gat_prep(const float* __restrict__ W,
                                               const float* __restrict__ a,
                                               const float* __restrict__ x,
                                               float* __restrict__ sd) {
    const int b = blockIdx.x;
    const int f = threadIdx.x;
    if (b < GAT_H) {
        const float wf = W[b * GAT_F + f];
        float ps = wf * a[b * 2 * GAT_F + f];
        float pd = wf * a[b * 2 * GAT_F + GAT_F + f];
        #pragma unroll
        for (int off = 32; off > 0; off >>= 1) {
            ps += __shfl_xor(ps, off, 64);
            pd += __shfl_xor(pd, off, 64);
        }
        if (f == 0) { sd[b] = ps; sd[GAT_H + b] = pd; }
    } else {
        float s = 0.0f;
        #pragma unroll
        for (int j = 0; j < GAT_N / 64; ++j) s += x[j * 64 + f];
        #pragma unroll
        for (int off = 32; off > 0; off >>= 1) s += __shfl_xor(s, off, 64);
        if (f == 0) sd[2 * GAT_H] = s * (1.0f / GAT_N);
    }
}

// Table, layout [h][j]: {B,D} = {exp2(L*d_h*x_j), exp2(0.2L*d_h*x_j)}.
// Consumer uses E = max(A*B, C*D) (exact: exp2 is monotone), so no swap.
__global__ __launch_bounds__(256) void gat_tab(const float* __restrict__ x,
                                               const float* __restrict__ sd,
                                               float2* __restrict__ tab) {
    const int t = blockIdx.x * 256 + threadIdx.x;    // 0..49151
    const int h = t >> 12;
    const int j = t & (GAT_N - 1);
    const float q = LOG2E * sd[GAT_H + h] * x[j];
    tab[t] = make_float2(__builtin_amdgcn_exp2f(q),
                         __builtin_amdgcn_exp2f(0.2f * q));
}

// Main: 4096 blocks = 1024 row-groups x 4 j-slices. Block = 4 rows x 1024 j.
// NO LDS, NO barriers. Waves split the 12 heads (3 each) so each wave owns
// complete j-slice sums for its (r,h) cells. Table read direct from global
// (L2-resident, 384 KB). adj/table/x in a 1-chunk rolling register pipeline.
// Body per (j,r,h): v_mul(sgpr) + v_mul(sgpr) + v_max + 2 v_fma. No trans.
__global__ __launch_bounds__(256, 4) void gat_main(const float* __restrict__ x,
                                                   const int* __restrict__ adj,
                                                   const float* __restrict__ sd,
                                                   const float2* __restrict__ tab,
                                                   float2* __restrict__ part) {
    const int tid  = threadIdx.x;
    const int lane = tid & 63;
    const int wq   = tid >> 6;
    const int rb   = blockIdx.x / NJB;
    const int jbs  = blockIdx.x % NJB;
    const int row0 = rb * RPB;
    const int j0   = jbs * JB;

    // Lane-parallel per-(r,k) constants -> SGPRs.
    // lanes 0..11 compute A=exp2(L*zi), lanes 32..43 compute C=exp2(0.2L*zi).
    float sA[RPB][HPW], sC[RPB][HPW];
    {
        const int il = lane & 31;
        float val = 0.0f;
        if (il < RPB * HPW) {
            const int rr = il / HPW, kk = il % HPW;
            const float zi = x[row0 + rr] * sd[wq * HPW + kk];
            val = __builtin_amdgcn_exp2f(((lane < 32) ? 1.0f : 0.2f) * LOG2E * zi);
        }
        #pragma unroll
        for (int r = 0; r < RPB; ++r)
            #pragma unroll
            for (int k = 0; k < HPW; ++k) {
                sA[r][k] = rdlane(val, r * HPW + k);
                sC[r][k] = rdlane(val, 32 + r * HPW + k);
            }
    }

    float2 acc[RPB][HPW];
    #pragma unroll
    for (int r = 0; r < RPB; ++r)
        #pragma unroll
        for (int k = 0; k < HPW; ++k) acc[r][k] = make_float2(0.0f, 0.0f);

    // Chunk pointers: lane owns 2 consecutive j per chunk.
    const float4* tg[HPW];
    #pragma unroll
    for (int k = 0; k < HPW; ++k)
        tg[k] = (const float4*)(tab + (size_t)(wq * HPW + k) * GAT_N + j0);
    const int2* ag[RPB];
    #pragma unroll
    for (int r = 0; r < RPB; ++r)
        ag[r] = (const int2*)(adj + (size_t)(row0 + r) * GAT_N + j0);
    const float2* xg = (const float2*)(x + j0);

    // Rolling 1-deep pipeline: chunk c computes while c+1 is in flight.
    float4 Tc[HPW], Tn[HPW];
    int2   Ac[RPB], An[RPB];
    float2 Xc, Xn;
    #pragma unroll
    for (int k = 0; k < HPW; ++k) Tc[k] = tg[k][lane];
    #pragma unroll
    for (int r = 0; r < RPB; ++r) Ac[r] = ag[r][lane];
    Xc = xg[lane];

    #pragma unroll 1
    for (int c = 0; c < NCH; ++c) {
        const int ni = ((c < NCH - 1) ? (c + 1) : c) * 64 + lane;  // clamped
        #pragma unroll
        for (int k = 0; k < HPW; ++k) Tn[k] = tg[k][ni];
        #pragma unroll
        for (int r = 0; r < RPB; ++r) An[r] = ag[r][ni];
        Xn = xg[ni];

        #pragma unroll
        for (int e = 0; e < 2; ++e) {
            const float xj = e ? Xc.y : Xc.x;
            float2 P[HPW];
            #pragma unroll
            for (int k = 0; k < HPW; ++k)
                P[k] = e ? make_float2(Tc[k].z, Tc[k].w)
                         : make_float2(Tc[k].x, Tc[k].y);
            #pragma unroll
            for (int r = 0; r < RPB; ++r) {
                const int   ai  = e ? Ac[r].y : Ac[r].x;
                const float m01 = (float)ai;          // adj in {0,1}
                const float xm  = xj * m01;
                #pragma unroll
                for (int k = 0; k < HPW; ++k) {
                    const float E = fmaxf(sA[r][k] * P[k].x, sC[r][k] * P[k].y);
                    acc[r][k].x = fmaf(E, m01, acc[r][k].x);
                    acc[r][k].y = fmaf(E, xm,  acc[r][k].y);
                }
            }
        }
        #pragma unroll
        for (int k = 0; k < HPW; ++k) Tc[k] = Tn[k];
        #pragma unroll
        for (int r = 0; r < RPB; ++r) Ac[r] = An[r];
        Xc = Xn;
    }

    // Wave-reduce each (r,k) cell; lane 0 stores the j-slice partial.
    #pragma unroll
    for (int r = 0; r < RPB; ++r)
        #pragma unroll
        for (int k = 0; k < HPW; ++k) {
            float dn = acc[r][k].x, nm = acc[r][k].y;
            #pragma unroll
            for (int off = 32; off > 0; off >>= 1) {
                dn += __shfl_xor(dn, off, 64);
                nm += __shfl_xor(nm, off, 64);
            }
            if (lane == 0)
                part[((size_t)(row0 + r) * GAT_H + wq * HPW + k) * NJB + jbs] =
                    make_float2(dn, nm);
        }
}

// Combine: block = 4 rows. Sum NJB j-slice partials, fallback, out = c * W.
__global__ __launch_bounds__(256) void gat_comb(const float2* __restrict__ part,
                                                const float* __restrict__ sd,
                                                const float* __restrict__ W,
                                                float* __restrict__ out) {
    __shared__ float2 pp[4 * GAT_H * NJB];   // 192 float2
    __shared__ float  cs[4 * GAT_H];
    const int tid = threadIdx.x;
    if (tid < 96)
        ((float4*)pp)[tid] =
            ((const float4*)(part + (size_t)blockIdx.x * 4 * GAT_H * NJB))[tid];
    __syncthreads();
    if (tid < 4 * GAT_H) {
        float dn = 0.0f, nm = 0.0f;
        #pragma unroll
        for (int u = 0; u < NJB; ++u) {
            const float2 p = pp[tid * NJB + u];
            dn += p.x; nm += p.y;
        }
        cs[tid] = dn > 0.0f ? nm / dn : sd[2 * GAT_H];
    }
    __syncthreads();
    const size_t base = (size_t)blockIdx.x * 4 * GAT_H * GAT_F;
    #pragma unroll
    for (int it = 0; it < 12; ++it) {
        const int flat = it * 256 + tid;          // 0..3071
        const int rem  = flat % (GAT_H * GAT_F);
        out[base + flat] = cs[(flat / (GAT_H * GAT_F)) * GAT_H + rem / GAT_F] * W[rem];
    }
}

extern "C" void kernel_launch(void* const* d_in, const int* in_sizes, int n_in,
                              void* d_out, int out_size, void* d_ws, size_t ws_size,
                              hipStream_t stream) {
    const float* x   = (const float*)d_in[0];
    const int*   adj = (const int*)d_in[1];
    const float* W   = (const float*)d_in[2];
    const float* a   = (const float*)d_in[3];
    float*  out  = (float*)d_out;
    float*  sd   = (float*)d_ws;                          // 25 floats
    float2* tab  = (float2*)((float*)d_ws + TAB_OFF);     // 384 KB, [h][j]
    float2* part = (float2*)((float*)d_ws + PART_OFF);    // 1.5 MB

    gat_prep<<<13, 64, 0, stream>>>(W, a, x, sd);
    gat_tab<<<(GAT_N * GAT_H) / 256, 256, 0, stream>>>(x, sd, tab);
    gat_main<<<(GAT_N / RPB) * NJB, 256, 0, stream>>>(x, adj, sd, tab, part);
    gat_comb<<<GAT_N / 4, 256, 0, stream>>>(part, sd, W, out);
}